// Round 8
// baseline (178.420 us; speedup 1.0000x reference)
//
#include <hip/hip_runtime.h>
#include <stdint.h>

namespace ct {
constexpr int B = 16, G = 50, A = 81920, T = 128;
constexpr int NB2 = 64;              // blocks per image in pass kernels
constexpr int CH2 = A / (NB2 * 256); // 5 chunks of 256 anchors per block
constexpr int CAPP = 16384;          // per-image positive candidate capacity
constexpr int CAPN = 16384;          // per-image neg >=T1 candidate capacity
constexpr int STG  = 2048;           // LDS staging for selection (bitonic max)
constexpr int NX = 16, NY = 20, NCELL = NX * NY;  // 64-px cells
constexpr float NEG_T1 = 0.992f;

// output offsets (in floats)
constexpr size_t O_DELTAS = 0;
constexpr size_t O_CLS = O_DELTAS + (size_t)B * T * 3;
constexpr size_t O_IND = O_CLS + (size_t)B * T * 2;
constexpr size_t O_SD  = O_IND + (size_t)B * T * 2;
constexpr size_t O_SI  = O_SD + (size_t)B * G * 3;
constexpr size_t O_GTN = O_SI + (size_t)B * G * 3;
constexpr size_t O_PN  = O_GTN + B;
constexpr size_t O_NN  = O_PN + B;

// ws layout (bytes). LEFT = 0xFF memset; [GTMAX..CT1] = single 0 memset;
// BCNT/PD*/NI written unconditionally. Contended counters on 64B lines.
constexpr size_t W_LEFT  = 0;        // B*G u64 (6400 B) -> memset 0xFF
constexpr size_t W_GTMAX = 8192;     // B*G u32 (3200)
constexpr size_t W_RIGHT = 11392;    // B*G u64 (6400)
constexpr size_t W_CPOS  = 17792;    // B lines (16 u32 stride, 1024)
constexpr size_t W_CT1   = 18816;    // B lines (1024)  [zero region ends 19840]
constexpr size_t W_ZERO0 = W_GTMAX;
constexpr size_t W_ZSIZE = 19840 - W_GTMAX;
constexpr size_t W_BCNT  = 19840;    // B*NB2 u32 (4096)
constexpr size_t W_POSL  = 24064;    // B*CAPP u64 (2 MB)
constexpr size_t W_NT1   = W_POSL + 8ull * B * CAPP;
} // namespace ct

struct U2 { uint32_t x, y; };

__device__ __forceinline__ U2 threefry(uint32_t k0, uint32_t k1, uint32_t x0, uint32_t x1) {
  uint32_t ks2 = k0 ^ k1 ^ 0x1BD11BDAu;
  x0 += k0; x1 += k1;
#define TFR(r) { x0 += x1; x1 = (x1 << (r)) | (x1 >> (32 - (r))); x1 ^= x0; }
  TFR(13) TFR(15) TFR(26) TFR(6)  x0 += k1;  x1 += ks2 + 1u;
  TFR(17) TFR(29) TFR(16) TFR(24) x0 += ks2; x1 += k0 + 2u;
  TFR(13) TFR(15) TFR(26) TFR(6)  x0 += k0;  x1 += k1 + 3u;
  TFR(17) TFR(29) TFR(16) TFR(24) x0 += k1;  x1 += ks2 + 4u;
  TFR(13) TFR(15) TFR(26) TFR(6)  x0 += ks2; x1 += k0 + 5u;
#undef TFR
  return {x0, x1};
}

__device__ __forceinline__ uint32_t rnd_bits(uint32_t ka, uint32_t kb, uint32_t idx) {
  U2 o = threefry(ka, kb, 0u, idx);
  return o.x ^ o.y;
}

// Shared by both passes: v = fl(inter/denom) bit-identical (contract off, IEEE div).
__device__ __forceinline__ void iou_parts(float g0, float g1, float g2, float g3,
                                          float garea,
                                          float a0, float a1, float a2, float a3,
                                          float aarea, float& inter, float& denom) {
#pragma clang fp contract(off)
  float iw = fminf(g3, a3) - fmaxf(g1, a1);
  iw = fmaxf(0.0f, iw);
  float ih = fminf(g2, a2) - fmaxf(g0, a0);
  ih = fmaxf(0.0f, ih);
  inter = iw * ih;
  denom = (garea + aarea) - inter;
}

// wave-0 compaction of tagged gts (identical order everywhere)
__device__ __forceinline__ void compact_gts(const float* gt_boxes, int b, int tid,
                                            float4* sgA, float* sgG, int* sgO,
                                            int* sn) {
  using namespace ct;
  int lane = tid & 63;
  if (tid < 64) {
    bool pred = false;
    float g0 = 0, g1 = 0, g2 = 0, g3 = 0;
    if (tid < G) {
      const float* gp = gt_boxes + ((size_t)b * G + tid) * 5;
      g0 = gp[0]; g1 = gp[1]; g2 = gp[2]; g3 = gp[3];
      pred = gp[4] > 0.0f;
    }
    unsigned long long mk = __ballot(pred);
    int slot = (int)__popcll(mk & ((1ull << lane) - 1ull));
    if (pred) {
      sgA[slot] = make_float4(g0, g1, g2, g3);
      sgG[slot] = (g3 - g1) * (g2 - g0);
      sgO[slot] = tid;
    }
    if (lane == 0) *sn = (int)__popcll(mk);
  }
}

// inline per-cell gt bitmask build (conservative bbox-cell cover, in LDS)
__device__ __forceinline__ void build_cellmask(const float4* sgA, int ntag, int tid,
                                               unsigned long long* sCM) {
  using namespace ct;
  for (int c = tid; c < NCELL; c += 256) {
    int cx = c & (NX - 1), cy = c >> 4;
    float x0 = cx * 64.0f, x1 = x0 + 64.0f;
    float y0 = cy * 64.0f, y1 = y0 + 64.0f;
    unsigned long long m = 0;
    for (int j = 0; j < ntag; ++j) {
      float4 g = sgA[j];  // y1,x1,y2,x2
      if (g.y < x1 && g.w > x0 && g.x < y1 && g.z > y0) m |= 1ull << j;
    }
    sCM[c] = m;
  }
}

__device__ __forceinline__ unsigned long long anchor_mask(const unsigned long long* sCM,
                                                          float4 an) {
  using namespace ct;
  int cx0 = min((int)an.y >> 6, NX - 1), cx1 = min((int)an.w >> 6, NX - 1);
  int cy0 = min((int)an.x >> 6, NY - 1), cy1 = min((int)an.z >> 6, NY - 1);
  unsigned long long mask = 0;
  for (int cy = cy0; cy <= cy1; ++cy)
    for (int cx = cx0; cx <= cx1; ++cx)
      mask |= sCM[cy * NX + cx];
  return mask;
}

// ---------------- K1b (pass 1): gt_max over masked pairs ----------------
__global__ __launch_bounds__(256) void k1b_gtmax(const float* __restrict__ anchors,
                                                 const float* __restrict__ gt_boxes,
                                                 char* ws) {
  using namespace ct;
  __shared__ float4 sgA[64];
  __shared__ float  sgG[64];
  __shared__ int    sgO[64];
  __shared__ int    sn;
  __shared__ uint32_t sGm[64];
  __shared__ unsigned long long sCM[NCELL];
  int b = blockIdx.y, tid = threadIdx.x;
  compact_gts(gt_boxes, b, tid, sgA, sgG, sgO, &sn);
  if (tid < 64) sGm[tid] = 0u;
  __syncthreads();
  build_cellmask(sgA, sn, tid, sCM);
  __syncthreads();
  const float4* ap = (const float4*)(anchors + (size_t)b * A * 4);
  for (int c = 0; c < CH2; ++c) {
    int a = (blockIdx.x * CH2 + c) * 256 + tid;
    float4 an = ap[a];
    float aarea = (an.w - an.y) * (an.z - an.x);
    unsigned long long mask = anchor_mask(sCM, an);
    while (mask) {
      int j = (int)(__ffsll((long long)mask) - 1);
      mask &= mask - 1;
      float4 g = sgA[j];
      float inter, denom;
      iou_parts(g.x, g.y, g.z, g.w, sgG[j], an.x, an.y, an.z, an.w, aarea, inter, denom);
      float v = inter / denom;
      if (v > 0.0f) atomicMax(&sGm[j], __float_as_uint(v));
    }
  }
  __syncthreads();
  if (tid < sn && sGm[tid] != 0u)
    atomicMax((uint32_t*)(ws + W_GTMAX) + (size_t)b * G + sgO[tid], sGm[tid]);
}

// ---------------- K2 (pass 2): pos/neg candidates ----------------
__global__ __launch_bounds__(256) void k2_posneg(const float* __restrict__ anchors,
                                                 const float* __restrict__ gt_boxes,
                                                 char* ws) {
  using namespace ct;
  __shared__ float4 sgA[64];
  __shared__ float  sgG[64];
  __shared__ int    sgO[64];
  __shared__ float  sgM[64];
  __shared__ int    sn;
  __shared__ unsigned long long sCM[NCELL];
  __shared__ uint32_t sK[4];            // threefry keys (computed inline)
  __shared__ uint32_t sT1C[CH2];        // per-chunk T1 count
  __shared__ uint32_t sWT1[CH2][4];     // per-chunk per-wave base
  __shared__ uint32_t sPfx[CH2];        // chunk prefix
  __shared__ uint32_t sNegW[4];         // per-wave neg totals
  __shared__ uint32_t sT1Base;
  int b = blockIdx.y, tid = threadIdx.x, lane = tid & 63, wid = tid >> 6;
  compact_gts(gt_boxes, b, tid, sgA, sgG, sgO, &sn);
  if (tid < CH2) sT1C[tid] = 0u;
  if (tid == 64 || (tid == 0 && blockDim.x == 64)) {}  // no-op
  if (tid == 65 % 256) {}
  if (tid == 66 % 256) {}
  if (tid == 0) {
    U2 kb = threefry(0u, 42u, 0u, (uint32_t)b);
    U2 s0 = threefry(kb.x, kb.y, 0u, 0u);
    U2 s1 = threefry(kb.x, kb.y, 0u, 1u);
    sK[0] = s0.x; sK[1] = s0.y;  // k1
    sK[2] = s1.x; sK[3] = s1.y;  // k2
  }
  __syncthreads();
  build_cellmask(sgA, sn, tid, sCM);
  __syncthreads();
  if (tid < sn)
    sgM[tid] = __uint_as_float(((const uint32_t*)(ws + W_GTMAX))[(size_t)b * G + sgO[tid]]);
  __syncthreads();

  uint32_t k1a = sK[0], k1b = sK[1], k2a = sK[2], k2b = sK[3];
  unsigned long long* posl  = (unsigned long long*)(ws + W_POSL) + (size_t)b * CAPP;
  unsigned long long* negt1 = (unsigned long long*)(ws + W_NT1)  + (size_t)b * CAPN;
  unsigned long long* left  = (unsigned long long*)(ws + W_LEFT)  + (size_t)b * G;
  unsigned long long* right = (unsigned long long*)(ws + W_RIGHT) + (size_t)b * G;
  const float4* ap = (const float4*)(anchors + (size_t)b * A * 4);

  unsigned long long nkv[CH2];
  uint32_t offv[CH2];
  bool t1v[CH2];
  uint32_t negAcc = 0;

  for (int c = 0; c < CH2; ++c) {
    int a = (blockIdx.x * CH2 + c) * 256 + tid;
    float4 an = ap[a];
    float aarea = (an.w - an.y) * (an.z - an.x);
    unsigned long long mask = anchor_mask(sCM, an);

    float amax = 0.0f;
    unsigned long long mEq = 0, mMax = 0;
    unsigned long long t0 = mask;
    while (t0) {
      int j = (int)(__ffsll((long long)t0) - 1);
      t0 &= t0 - 1;
      float4 g = sgA[j];
      float inter, denom;
      iou_parts(g.x, g.y, g.z, g.w, sgG[j], an.x, an.y, an.z, an.w, aarea, inter, denom);
      float v = inter / denom;     // bit-identical to pass 1's v
      mEq |= (v == sgM[j]) ? (1ull << j) : 0ull;
      if (v > amax) { amax = v; mMax = 1ull << j; }
      else mMax |= (v == amax) ? (1ull << j) : 0ull;
    }
    unsigned long long pm = mEq | (amax >= 0.7f ? mMax : 0ull);

    // positives: rare -> per-candidate atomics on padded lines
    if (__ballot(pm != 0)) {
      unsigned long long t = pm;
      while (t) {
        int j = (int)(__ffsll((long long)t) - 1);
        t &= t - 1;
        int g = sgO[j];
        uint32_t jg = (uint32_t)g * (uint32_t)A + (uint32_t)a;
        uint32_t m = rnd_bits(k1a, k1b, jg) >> 9;
        unsigned long long pk = ((unsigned long long)(m + 1u) << 32) | (0xFFFFFFFFu - jg);
        uint32_t idx = atomicAdd((uint32_t*)(ws + W_CPOS) + b * 16, 1u);
        if (idx < (uint32_t)CAPP) posl[idx] = pk;
        unsigned long long x1b = (unsigned long long)__float_as_uint(an.y);
        atomicMin(left + g,  (x1b << 32) | (uint32_t)a);
        atomicMax(right + g, (x1b << 32) | (0xFFFFFFFFu - (uint32_t)a));
      }
    }

    bool isneg = (amax < 0.5f) && (pm == 0);
    uint32_t m2 = rnd_bits(k2a, k2b, (uint32_t)a) >> 9;
    nkv[c] = ((unsigned long long)(m2 + 1u) << 32) | (0xFFFFFFFFu - (uint32_t)a);
    t1v[c] = isneg && ((float)m2 * (1.0f / 8388608.0f) >= NEG_T1);
    unsigned long long nm = __ballot(isneg);
    unsigned long long tm = __ballot(t1v[c]);
    offv[c] = (uint32_t)__popcll(tm & ((1ull << lane) - 1ull));
    if (lane == 0) {
      negAcc += (uint32_t)__popcll(nm);
      sWT1[c][wid] = atomicAdd(&sT1C[c], (uint32_t)__popcll(tm));
    }
  }
  if (lane == 0) sNegW[wid] = negAcc;
  __syncthreads();
  if (tid == 0) {
    uint32_t tot = 0;
    for (int c = 0; c < CH2; ++c) { sPfx[c] = tot; tot += sT1C[c]; }
    sT1Base = tot ? atomicAdd((uint32_t*)(ws + W_CT1) + b * 16, tot) : 0u;
    ((uint32_t*)(ws + W_BCNT))[b * NB2 + blockIdx.x] =
        sNegW[0] + sNegW[1] + sNegW[2] + sNegW[3];
  }
  __syncthreads();
  uint32_t base = sT1Base;
  for (int c = 0; c < CH2; ++c) {
    if (t1v[c]) {
      uint32_t idx = base + sPfx[c] + sWT1[c][wid] + offv[c];
      if (idx < (uint32_t)CAPN) negt1[idx] = nkv[c];
    }
  }
}

// iterative top-64 fallback (n may exceed LDS stage); 2 barriers/iteration
__device__ void select_top64(const unsigned long long* gsrc, int n,
                             unsigned long long* stage, unsigned long long* sel,
                             unsigned long long* wmax) {
  using namespace ct;
  int tid = threadIdx.x, lane = tid & 63, wid = tid >> 6;
  const unsigned long long* p = gsrc;
  if (n <= STG) {
    for (int i = tid; i < n; i += 256) stage[i] = gsrc[i];
    p = stage;
  }
  __syncthreads();
  unsigned long long prev = ~0ull;
  for (int k = 0; k < 64; ++k) {
    unsigned long long lm = 0;
    for (int i = tid; i < n; i += 256) {
      unsigned long long v = p[i];
      if (v < prev && v > lm) lm = v;
    }
#pragma unroll
    for (int off = 32; off >= 1; off >>= 1) {
      unsigned long long o = __shfl_xor(lm, off, 64);
      if (o > lm) lm = o;
    }
    if (lane == 0) wmax[wid] = lm;
    __syncthreads();
    if (tid == 0) {
      unsigned long long m = wmax[0];
      for (int w = 1; w < 4; ++w) if (wmax[w] > m) m = wmax[w];
      sel[k] = m;
    }
    __syncthreads();
    prev = sel[k];
  }
}

// descending bitonic sort in LDS for n<=STG unique keys
__device__ void bitonic_desc(const unsigned long long* gsrc, int n,
                             unsigned long long* stage) {
  int tid = threadIdx.x;
  int sz = 64;
  while (sz < n) sz <<= 1;
  for (int i = tid; i < sz; i += 256) stage[i] = (i < n) ? gsrc[i] : 0ull;
  __syncthreads();
  for (int k = 2; k <= sz; k <<= 1) {
    for (int j = k >> 1; j > 0; j >>= 1) {
      for (int i = tid; i < sz; i += 256) {
        int l = i ^ j;
        if (l > i) {
          unsigned long long a = stage[i], c = stage[l];
          bool dir = (i & k) == 0;
          if ((a < c) == dir) { stage[i] = c; stage[l] = a; }
        }
      }
      __syncthreads();
    }
  }
}

// ---------------- K345: pos select + neg select + output assembly (1 block/image) ----
__global__ __launch_bounds__(256) void k345_out(const float* __restrict__ anchors,
                                                const float* __restrict__ gt_boxes,
                                                const float* __restrict__ gt_cls,
                                                const int* __restrict__ vidx,
                                                char* ws, float* __restrict__ out) {
  using namespace ct;
  __shared__ unsigned long long stage[STG];
  __shared__ unsigned long long sel[64];
  __shared__ unsigned long long wmax[4];
  __shared__ uint32_t scnt[4];
  __shared__ float sPD0[64], sPD1[64], sPC[64], sIPF[64];
  __shared__ int sNI[64];
  __shared__ int sPn, sNn;
  int b = blockIdx.x, tid = threadIdx.x, lane = tid & 63, wid = tid >> 6;

  // ---- phase A: positive selection ----
  {
    int n = (int)min(((const uint32_t*)(ws + W_CPOS))[b * 16], (uint32_t)CAPP);
    const unsigned long long* src = (const unsigned long long*)(ws + W_POSL) + (size_t)b * CAPP;
    if (n <= STG) {
      bitonic_desc(src, n, stage);
      if (tid < 64) sel[tid] = stage[tid];
      __syncthreads();
    } else {
      select_top64(src, n, stage, sel, wmax);
    }
    int npos = n < 64 ? n : 64;
    if (tid == 0) sPn = npos;
    if (tid < 64) {
      float pd0 = 0.0f, pd1 = 0.0f, pcv = 0.0f, ipf = 0.0f;
      if (tid < npos) {
        uint32_t j = 0xFFFFFFFFu - (uint32_t)sel[tid];
        int g = j / (uint32_t)A, a = j % (uint32_t)A;
        const float* gp = gt_boxes + ((size_t)b * G + g) * 5;
        float4 an = *(const float4*)(anchors + ((size_t)b * A + a) * 4);
        float h = an.z - an.x;
        float gt_h = gp[2] - gp[0];
        float dy = (gp[2] + gp[0] - (an.z + an.x)) * 0.5f / h;
        float dh = logf(gt_h / h);
        pd0 = dy / 0.1f;
        pd1 = dh / 0.2f;
        pcv = gt_cls[((size_t)b * G + g) * 2];
        ipf = (float)vidx[(size_t)b * A + a];
      }
      sPD0[tid] = pd0; sPD1[tid] = pd1; sPC[tid] = pcv; sIPF[tid] = ipf;
    }
  }
  __syncthreads();

  // ---- phase B: negative selection ----
  {
    const uint32_t* bc = (const uint32_t*)(ws + W_BCNT) + (size_t)b * NB2;
    uint32_t callv = 0;
    for (int i = tid; i < NB2; i += 256) callv += bc[i];
#pragma unroll
    for (int off = 32; off >= 1; off >>= 1) callv += __shfl_xor(callv, off, 64);
    if (lane == 0) scnt[wid] = callv;
    __syncthreads();
    int call = (int)(scnt[0] + scnt[1] + scnt[2] + scnt[3]);
    int c1 = (int)min(((const uint32_t*)(ws + W_CT1))[b * 16], (uint32_t)CAPN);
    if (c1 <= STG) {
      bitonic_desc((const unsigned long long*)(ws + W_NT1) + (size_t)b * CAPN, c1, stage);
      if (tid < 64) sel[tid] = stage[tid];
      __syncthreads();
    } else {
      select_top64((const unsigned long long*)(ws + W_NT1) + (size_t)b * CAPN, c1,
                   stage, sel, wmax);
    }
    int nn = call < 64 ? call : 64;
    if (nn > c1) nn = c1;   // paranoid clamp; c1>=64 in practice
    if (tid == 0) sNn = nn;
    if (tid < 64) {
      int v = 0;
      if (tid < nn) v = (int)(0xFFFFFFFFu - (uint32_t)sel[tid]);
      sNI[tid] = v;
    }
  }
  __syncthreads();

  // ---- phase C: output assembly ----
  int pn = sPn, nn = sNn;
  if (tid < T) {
    int t = tid;
    bool ispos = t < pn;
    bool isneg = (t >= pn) && (t < pn + nn);
    float tagc = (ispos || isneg) ? 1.0f : 0.0f;
    int tp = t < 63 ? t : 63;
    float d0 = ispos ? sPD0[tp] : 0.0f;
    float d1 = ispos ? sPD1[tp] : 0.0f;
    out[O_DELTAS + ((size_t)b * T + t) * 3 + 0] = d0;
    out[O_DELTAS + ((size_t)b * T + t) * 3 + 1] = d1;
    out[O_DELTAS + ((size_t)b * T + t) * 3 + 2] = tagc;
    out[O_CLS + ((size_t)b * T + t) * 2 + 0] = ispos ? sPC[tp] : 0.0f;
    out[O_CLS + ((size_t)b * T + t) * 2 + 1] = tagc;
    float iv = 0.0f, itag = 0.0f;
    if (ispos) { iv = sIPF[tp]; itag = 1.0f; }
    else if (isneg) {
      int nj = t - pn; nj = nj < 63 ? nj : 63;
      iv = (float)sNI[nj]; itag = -1.0f;
    }
    out[O_IND + ((size_t)b * T + t) * 2 + 0] = iv;
    out[O_IND + ((size_t)b * T + t) * 2 + 1] = itag;
  }
  if (tid >= 128 && tid < 128 + G) {
    int g = tid - 128;
    const float* gp = gt_boxes + ((size_t)b * G + g) * 5;
    float tag = gp[4] > 0.0f ? 1.0f : 0.0f;
    float sd0 = 0.0f, sd1 = 0.0f, si0 = 0.0f, si1 = 0.0f;
    if (tag > 0.0f) {
      unsigned long long lp = ((const unsigned long long*)(ws + W_LEFT))[(size_t)b * G + g];
      unsigned long long rp = ((const unsigned long long*)(ws + W_RIGHT))[(size_t)b * G + g];
      int al = (int)(uint32_t)lp;
      int ar = (int)(0xFFFFFFFFu - (uint32_t)rp);
      float4 la = *(const float4*)(anchors + ((size_t)b * A + al) * 4);
      float4 ra = *(const float4*)(anchors + ((size_t)b * A + ar) * 4);
      sd0 = (gp[1] - (la.w + la.y) * 0.5f) / (la.w - la.y) / 0.1f;
      sd1 = (gp[3] - (ra.w + ra.y) * 0.5f) / (ra.w - ra.y) / 0.1f;
      si0 = (float)vidx[(size_t)b * A + al];
      si1 = (float)vidx[(size_t)b * A + ar];
    }
    out[O_SD + ((size_t)b * G + g) * 3 + 0] = sd0;
    out[O_SD + ((size_t)b * G + g) * 3 + 1] = sd1;
    out[O_SD + ((size_t)b * G + g) * 3 + 2] = tag;
    out[O_SI + ((size_t)b * G + g) * 3 + 0] = si0;
    out[O_SI + ((size_t)b * G + g) * 3 + 1] = si1;
    out[O_SI + ((size_t)b * G + g) * 3 + 2] = tag;
  }
  if (tid == 190) {
    float s = 0.0f;
    for (int g = 0; g < G; ++g)
      s += (gt_boxes[((size_t)b * G + g) * 5 + 4] > 0.0f) ? 1.0f : 0.0f;
    out[O_GTN + b] = s;
  }
  if (tid == 191) out[O_PN + b] = (float)pn;
  if (tid == 192) out[O_NN + b] = (float)nn;
}

extern "C" void kernel_launch(void* const* d_in, const int* in_sizes, int n_in,
                              void* d_out, int out_size, void* d_ws, size_t ws_size,
                              hipStream_t stream) {
  using namespace ct;
  (void)in_sizes; (void)n_in; (void)out_size; (void)ws_size;
  const float* gt_boxes = (const float*)d_in[0];
  const float* gt_cls   = (const float*)d_in[1];
  const float* anchors  = (const float*)d_in[2];
  const int*   vidx     = (const int*)d_in[3];
  float* out = (float*)d_out;
  char* ws = (char*)d_ws;

  hipMemsetAsync(ws + W_LEFT, 0xFF, 8ull * B * G, stream);   // LEFT = ~0
  hipMemsetAsync(ws + W_ZERO0, 0, W_ZSIZE, stream);          // GTMAX/RIGHT/CPOS/CT1
  k1b_gtmax<<<dim3(NB2, B), dim3(256), 0, stream>>>(anchors, gt_boxes, ws);
  k2_posneg<<<dim3(NB2, B), dim3(256), 0, stream>>>(anchors, gt_boxes, ws);
  k345_out<<<dim3(B), dim3(256), 0, stream>>>(anchors, gt_boxes, gt_cls, vidx, ws, out);
}

// Round 9
// 167.482 us; speedup vs baseline: 1.0653x; 1.0653x over previous
//
#include <hip/hip_runtime.h>
#include <stdint.h>

namespace ct {
constexpr int B = 16, G = 50, A = 81920, T = 128;
constexpr int NB2 = 64;              // blocks per image in pass kernels
constexpr int CH2 = A / (NB2 * 256); // 5 chunks of 256 anchors per block
constexpr int CAPP = 16384;          // per-image positive candidate capacity
constexpr int CAPN = 16384;          // per-image neg >=T1 candidate capacity
constexpr int STG  = 2048;           // LDS staging for selection (bitonic max)
constexpr int NX = 16, NY = 20, NCELL = NX * NY;  // 64-px cells
constexpr float NEG_T1 = 0.992f;

// output offsets (in floats)
constexpr size_t O_DELTAS = 0;
constexpr size_t O_CLS = O_DELTAS + (size_t)B * T * 3;
constexpr size_t O_IND = O_CLS + (size_t)B * T * 2;
constexpr size_t O_SD  = O_IND + (size_t)B * T * 2;
constexpr size_t O_SI  = O_SD + (size_t)B * G * 3;
constexpr size_t O_GTN = O_SI + (size_t)B * G * 3;
constexpr size_t O_PN  = O_GTN + B;
constexpr size_t O_NN  = O_PN + B;

// ws offsets (bytes). Contended counters padded to a 64B line per image.
constexpr size_t W_KEYS  = 0;                         // B*4 u32
constexpr size_t W_GTMAX = 256;                       // B*G u32 (float bits)
constexpr size_t W_LEFT  = 4096;                      // B*G u64
constexpr size_t W_RIGHT = 10496;                     // B*G u64
constexpr size_t W_CPOS  = 17408;                     // B lines (16 u32 stride)
constexpr size_t W_CT1   = 18432;                     // B lines
constexpr size_t W_BCNT  = 19584;                     // B*NB2 u32
constexpr size_t W_POSL  = 24064;                     // B*CAPP u64 (2 MB)
constexpr size_t W_NT1   = W_POSL + 8ull * B * CAPP;  // B*CAPN u64
constexpr size_t W_CMASK = W_NT1  + 8ull * B * CAPN;  // B*NCELL u64
} // namespace ct

struct U2 { uint32_t x, y; };

__device__ __forceinline__ U2 threefry(uint32_t k0, uint32_t k1, uint32_t x0, uint32_t x1) {
  uint32_t ks2 = k0 ^ k1 ^ 0x1BD11BDAu;
  x0 += k0; x1 += k1;
#define TFR(r) { x0 += x1; x1 = (x1 << (r)) | (x1 >> (32 - (r))); x1 ^= x0; }
  TFR(13) TFR(15) TFR(26) TFR(6)  x0 += k1;  x1 += ks2 + 1u;
  TFR(17) TFR(29) TFR(16) TFR(24) x0 += ks2; x1 += k0 + 2u;
  TFR(13) TFR(15) TFR(26) TFR(6)  x0 += k0;  x1 += k1 + 3u;
  TFR(17) TFR(29) TFR(16) TFR(24) x0 += k1;  x1 += ks2 + 4u;
  TFR(13) TFR(15) TFR(26) TFR(6)  x0 += ks2; x1 += k0 + 5u;
#undef TFR
  return {x0, x1};
}

__device__ __forceinline__ uint32_t rnd_bits(uint32_t ka, uint32_t kb, uint32_t idx) {
  U2 o = threefry(ka, kb, 0u, idx);
  return o.x ^ o.y;
}

// Shared by both passes: v = fl(inter/denom) bit-identical (contract off, IEEE div).
__device__ __forceinline__ void iou_parts(float g0, float g1, float g2, float g3,
                                          float garea,
                                          float a0, float a1, float a2, float a3,
                                          float aarea, float& inter, float& denom) {
#pragma clang fp contract(off)
  float iw = fminf(g3, a3) - fmaxf(g1, a1);
  iw = fmaxf(0.0f, iw);
  float ih = fminf(g2, a2) - fmaxf(g0, a0);
  ih = fmaxf(0.0f, ih);
  inter = iw * ih;
  denom = (garea + aarea) - inter;
}

// wave-0 compaction of tagged gts (identical order everywhere)
__device__ __forceinline__ void compact_gts(const float* gt_boxes, int b, int tid,
                                            float4* sgA, float* sgG, int* sgO,
                                            int* sn) {
  using namespace ct;
  int lane = tid & 63;
  if (tid < 64) {
    bool pred = false;
    float g0 = 0, g1 = 0, g2 = 0, g3 = 0;
    if (tid < G) {
      const float* gp = gt_boxes + ((size_t)b * G + tid) * 5;
      g0 = gp[0]; g1 = gp[1]; g2 = gp[2]; g3 = gp[3];
      pred = gp[4] > 0.0f;
    }
    unsigned long long mk = __ballot(pred);
    int slot = (int)__popcll(mk & ((1ull << lane) - 1ull));
    if (pred) {
      sgA[slot] = make_float4(g0, g1, g2, g3);
      sgG[slot] = (g3 - g1) * (g2 - g0);
      sgO[slot] = tid;
    }
    if (lane == 0) *sn = (int)__popcll(mk);
  }
}

// ---------------- K01: init + per-cell gt bitmask (once per image) ----------------
__global__ __launch_bounds__(256) void k01_init(const float* __restrict__ gt_boxes,
                                                char* ws) {
  using namespace ct;
  __shared__ float4 sgA[64];
  __shared__ float  sgG[64];
  __shared__ int    sgO[64];
  __shared__ int    sn;
  int b = blockIdx.x, tid = threadIdx.x;
  if (tid == 0) {
    uint32_t* keys = (uint32_t*)(ws + W_KEYS);
    U2 kb = threefry(0u, 42u, 0u, (uint32_t)b);
    U2 s0 = threefry(kb.x, kb.y, 0u, 0u);
    U2 s1 = threefry(kb.x, kb.y, 0u, 1u);
    keys[b * 4 + 0] = s0.x; keys[b * 4 + 1] = s0.y; // k1
    keys[b * 4 + 2] = s1.x; keys[b * 4 + 3] = s1.y; // k2
    ((uint32_t*)(ws + W_CPOS))[b * 16] = 0u;
    ((uint32_t*)(ws + W_CT1))[b * 16] = 0u;
  }
  if (tid >= 64 && tid < 64 + G) {
    int i = tid - 64;
    ((unsigned long long*)(ws + W_LEFT))[(size_t)b * G + i] = ~0ull;
    ((unsigned long long*)(ws + W_RIGHT))[(size_t)b * G + i] = 0ull;
    ((uint32_t*)(ws + W_GTMAX))[(size_t)b * G + i] = 0u;
  }
  compact_gts(gt_boxes, b, tid, sgA, sgG, sgO, &sn);
  __syncthreads();
  int ntag = sn;
  unsigned long long* cm = (unsigned long long*)(ws + W_CMASK) + (size_t)b * NCELL;
  for (int c = tid; c < NCELL; c += 256) {
    int cx = c & (NX - 1), cy = c >> 4;
    float x0 = cx * 64.0f, x1 = x0 + 64.0f;
    float y0 = cy * 64.0f, y1 = y0 + 64.0f;
    unsigned long long m = 0;
    for (int j = 0; j < ntag; ++j) {
      float4 g = sgA[j];  // y1,x1,y2,x2
      if (g.y < x1 && g.w > x0 && g.x < y1 && g.z > y0) m |= 1ull << j;
    }
    cm[c] = m;
  }
}

__device__ __forceinline__ unsigned long long anchor_mask(const unsigned long long* sCM,
                                                          float4 an) {
  using namespace ct;
  int cx0 = min((int)an.y >> 6, NX - 1), cx1 = min((int)an.w >> 6, NX - 1);
  int cy0 = min((int)an.x >> 6, NY - 1), cy1 = min((int)an.z >> 6, NY - 1);
  unsigned long long mask = 0;
  for (int cy = cy0; cy <= cy1; ++cy)
    for (int cx = cx0; cx <= cx1; ++cx)
      mask |= sCM[cy * NX + cx];
  return mask;
}

// ---------------- K1b (pass 1): gt_max over masked pairs ----------------
__global__ __launch_bounds__(256) void k1b_gtmax(const float* __restrict__ anchors,
                                                 const float* __restrict__ gt_boxes,
                                                 char* ws) {
  using namespace ct;
  __shared__ float4 sgA[64];
  __shared__ float  sgG[64];
  __shared__ int    sgO[64];
  __shared__ int    sn;
  __shared__ uint32_t sGm[64];
  __shared__ unsigned long long sCM[NCELL];
  int b = blockIdx.y, tid = threadIdx.x;
  compact_gts(gt_boxes, b, tid, sgA, sgG, sgO, &sn);
  if (tid < 64) sGm[tid] = 0u;
  const unsigned long long* cm = (const unsigned long long*)(ws + W_CMASK) + (size_t)b * NCELL;
  for (int c = tid; c < NCELL; c += 256) sCM[c] = cm[c];
  __syncthreads();
  const float4* ap = (const float4*)(anchors + (size_t)b * A * 4);
  for (int c = 0; c < CH2; ++c) {
    int a = (blockIdx.x * CH2 + c) * 256 + tid;
    float4 an = ap[a];
    float aarea = (an.w - an.y) * (an.z - an.x);
    unsigned long long mask = anchor_mask(sCM, an);
    while (mask) {
      int j = (int)(__ffsll((long long)mask) - 1);
      mask &= mask - 1;
      float4 g = sgA[j];
      float inter, denom;
      iou_parts(g.x, g.y, g.z, g.w, sgG[j], an.x, an.y, an.z, an.w, aarea, inter, denom);
      float v = inter / denom;
      if (v > 0.0f) atomicMax(&sGm[j], __float_as_uint(v));
    }
  }
  __syncthreads();
  if (tid < sn && sGm[tid] != 0u)
    atomicMax((uint32_t*)(ws + W_GTMAX) + (size_t)b * G + sgO[tid], sGm[tid]);
}

// ---------------- K2 (pass 2): pos/neg candidates ----------------
__global__ __launch_bounds__(256) void k2_posneg(const float* __restrict__ anchors,
                                                 const float* __restrict__ gt_boxes,
                                                 char* ws) {
  using namespace ct;
  __shared__ float4 sgA[64];
  __shared__ float  sgG[64];
  __shared__ int    sgO[64];
  __shared__ float  sgM[64];
  __shared__ int    sn;
  __shared__ unsigned long long sCM[NCELL];
  __shared__ uint32_t sT1C[CH2];        // per-chunk T1 count
  __shared__ uint32_t sWT1[CH2][4];     // per-chunk per-wave base
  __shared__ uint32_t sPfx[CH2];        // chunk prefix
  __shared__ uint32_t sNegW[4];         // per-wave neg totals
  __shared__ uint32_t sT1Base;
  int b = blockIdx.y, tid = threadIdx.x, lane = tid & 63, wid = tid >> 6;
  compact_gts(gt_boxes, b, tid, sgA, sgG, sgO, &sn);
  if (tid < CH2) sT1C[tid] = 0u;
  const unsigned long long* cm = (const unsigned long long*)(ws + W_CMASK) + (size_t)b * NCELL;
  for (int c = tid; c < NCELL; c += 256) sCM[c] = cm[c];
  __syncthreads();
  if (tid < sn)
    sgM[tid] = __uint_as_float(((const uint32_t*)(ws + W_GTMAX))[(size_t)b * G + sgO[tid]]);
  __syncthreads();

  const uint32_t* keys = (const uint32_t*)(ws + W_KEYS);
  uint32_t k1a = keys[b * 4 + 0], k1b = keys[b * 4 + 1];
  uint32_t k2a = keys[b * 4 + 2], k2b = keys[b * 4 + 3];
  unsigned long long* posl  = (unsigned long long*)(ws + W_POSL) + (size_t)b * CAPP;
  unsigned long long* negt1 = (unsigned long long*)(ws + W_NT1)  + (size_t)b * CAPN;
  unsigned long long* left  = (unsigned long long*)(ws + W_LEFT)  + (size_t)b * G;
  unsigned long long* right = (unsigned long long*)(ws + W_RIGHT) + (size_t)b * G;
  const float4* ap = (const float4*)(anchors + (size_t)b * A * 4);

  unsigned long long nkv[CH2];
  uint32_t offv[CH2];
  bool t1v[CH2];
  uint32_t negAcc = 0;

  for (int c = 0; c < CH2; ++c) {
    int a = (blockIdx.x * CH2 + c) * 256 + tid;
    float4 an = ap[a];
    float aarea = (an.w - an.y) * (an.z - an.x);
    unsigned long long mask = anchor_mask(sCM, an);

    float amax = 0.0f;
    unsigned long long mEq = 0, mMax = 0;
    unsigned long long t0 = mask;
    while (t0) {
      int j = (int)(__ffsll((long long)t0) - 1);
      t0 &= t0 - 1;
      float4 g = sgA[j];
      float inter, denom;
      iou_parts(g.x, g.y, g.z, g.w, sgG[j], an.x, an.y, an.z, an.w, aarea, inter, denom);
      float v = inter / denom;     // bit-identical to pass 1's v
      mEq |= (v == sgM[j]) ? (1ull << j) : 0ull;
      if (v > amax) { amax = v; mMax = 1ull << j; }
      else mMax |= (v == amax) ? (1ull << j) : 0ull;
    }
    unsigned long long pm = mEq | (amax >= 0.7f ? mMax : 0ull);

    // positives: rare -> per-candidate atomics on padded lines
    if (__ballot(pm != 0)) {
      unsigned long long t = pm;
      while (t) {
        int j = (int)(__ffsll((long long)t) - 1);
        t &= t - 1;
        int g = sgO[j];
        uint32_t jg = (uint32_t)g * (uint32_t)A + (uint32_t)a;
        uint32_t m = rnd_bits(k1a, k1b, jg) >> 9;
        unsigned long long pk = ((unsigned long long)(m + 1u) << 32) | (0xFFFFFFFFu - jg);
        uint32_t idx = atomicAdd((uint32_t*)(ws + W_CPOS) + b * 16, 1u);
        if (idx < (uint32_t)CAPP) posl[idx] = pk;
        unsigned long long x1b = (unsigned long long)__float_as_uint(an.y);
        atomicMin(left + g,  (x1b << 32) | (uint32_t)a);
        atomicMax(right + g, (x1b << 32) | (0xFFFFFFFFu - (uint32_t)a));
      }
    }

    bool isneg = (amax < 0.5f) && (pm == 0);
    uint32_t m2 = rnd_bits(k2a, k2b, (uint32_t)a) >> 9;
    nkv[c] = ((unsigned long long)(m2 + 1u) << 32) | (0xFFFFFFFFu - (uint32_t)a);
    t1v[c] = isneg && ((float)m2 * (1.0f / 8388608.0f) >= NEG_T1);
    unsigned long long nm = __ballot(isneg);
    unsigned long long tm = __ballot(t1v[c]);
    offv[c] = (uint32_t)__popcll(tm & ((1ull << lane) - 1ull));
    if (lane == 0) {
      negAcc += (uint32_t)__popcll(nm);
      sWT1[c][wid] = atomicAdd(&sT1C[c], (uint32_t)__popcll(tm));
    }
  }
  if (lane == 0) sNegW[wid] = negAcc;
  __syncthreads();
  if (tid == 0) {
    uint32_t tot = 0;
    for (int c = 0; c < CH2; ++c) { sPfx[c] = tot; tot += sT1C[c]; }
    sT1Base = tot ? atomicAdd((uint32_t*)(ws + W_CT1) + b * 16, tot) : 0u;
    ((uint32_t*)(ws + W_BCNT))[b * NB2 + blockIdx.x] =
        sNegW[0] + sNegW[1] + sNegW[2] + sNegW[3];
  }
  __syncthreads();
  uint32_t base = sT1Base;
  for (int c = 0; c < CH2; ++c) {
    if (t1v[c]) {
      uint32_t idx = base + sPfx[c] + sWT1[c][wid] + offv[c];
      if (idx < (uint32_t)CAPN) negt1[idx] = nkv[c];
    }
  }
}

// iterative top-64 fallback (n may exceed LDS stage); 2 barriers/iteration
__device__ void select_top64(const unsigned long long* gsrc, int n,
                             unsigned long long* stage, unsigned long long* sel,
                             unsigned long long* wmax) {
  using namespace ct;
  int tid = threadIdx.x, lane = tid & 63, wid = tid >> 6;
  const unsigned long long* p = gsrc;
  if (n <= STG) {
    for (int i = tid; i < n; i += 256) stage[i] = gsrc[i];
    p = stage;
  }
  __syncthreads();
  unsigned long long prev = ~0ull;
  for (int k = 0; k < 64; ++k) {
    unsigned long long lm = 0;
    for (int i = tid; i < n; i += 256) {
      unsigned long long v = p[i];
      if (v < prev && v > lm) lm = v;
    }
#pragma unroll
    for (int off = 32; off >= 1; off >>= 1) {
      unsigned long long o = __shfl_xor(lm, off, 64);
      if (o > lm) lm = o;
    }
    if (lane == 0) wmax[wid] = lm;
    __syncthreads();
    if (tid == 0) {
      unsigned long long m = wmax[0];
      for (int w = 1; w < 4; ++w) if (wmax[w] > m) m = wmax[w];
      sel[k] = m;
    }
    __syncthreads();
    prev = sel[k];
  }
}

// descending bitonic sort in LDS for n<=STG unique keys
__device__ void bitonic_desc(const unsigned long long* gsrc, int n,
                             unsigned long long* stage) {
  int tid = threadIdx.x;
  int sz = 64;
  while (sz < n) sz <<= 1;
  for (int i = tid; i < sz; i += 256) stage[i] = (i < n) ? gsrc[i] : 0ull;
  __syncthreads();
  for (int k = 2; k <= sz; k <<= 1) {
    for (int j = k >> 1; j > 0; j >>= 1) {
      for (int i = tid; i < sz; i += 256) {
        int l = i ^ j;
        if (l > i) {
          unsigned long long a = stage[i], c = stage[l];
          bool dir = (i & k) == 0;
          if ((a < c) == dir) { stage[i] = c; stage[l] = a; }
        }
      }
      __syncthreads();
    }
  }
}

// ---------------- K345: pos select + neg select + output assembly (1 block/image) ----
__global__ __launch_bounds__(256) void k345_out(const float* __restrict__ anchors,
                                                const float* __restrict__ gt_boxes,
                                                const float* __restrict__ gt_cls,
                                                const int* __restrict__ vidx,
                                                char* ws, float* __restrict__ out) {
  using namespace ct;
  __shared__ unsigned long long stage[STG];
  __shared__ unsigned long long sel[64];
  __shared__ unsigned long long wmax[4];
  __shared__ uint32_t scnt[4];
  __shared__ float sPD0[64], sPD1[64], sPC[64], sIPF[64];
  __shared__ int sNI[64];
  __shared__ int sPn, sNn;
  int b = blockIdx.x, tid = threadIdx.x, lane = tid & 63, wid = tid >> 6;

  // ---- phase A: positive selection ----
  {
    int n = (int)min(((const uint32_t*)(ws + W_CPOS))[b * 16], (uint32_t)CAPP);
    const unsigned long long* src = (const unsigned long long*)(ws + W_POSL) + (size_t)b * CAPP;
    if (n <= STG) {
      bitonic_desc(src, n, stage);
      if (tid < 64) sel[tid] = stage[tid];
      __syncthreads();
    } else {
      select_top64(src, n, stage, sel, wmax);
    }
    int npos = n < 64 ? n : 64;
    if (tid == 0) sPn = npos;
    if (tid < 64) {
      float pd0 = 0.0f, pd1 = 0.0f, pcv = 0.0f, ipf = 0.0f;
      if (tid < npos) {
        uint32_t j = 0xFFFFFFFFu - (uint32_t)sel[tid];
        int g = j / (uint32_t)A, a = j % (uint32_t)A;
        const float* gp = gt_boxes + ((size_t)b * G + g) * 5;
        float4 an = *(const float4*)(anchors + ((size_t)b * A + a) * 4);
        float h = an.z - an.x;
        float gt_h = gp[2] - gp[0];
        float dy = (gp[2] + gp[0] - (an.z + an.x)) * 0.5f / h;
        float dh = logf(gt_h / h);
        pd0 = dy / 0.1f;
        pd1 = dh / 0.2f;
        pcv = gt_cls[((size_t)b * G + g) * 2];
        ipf = (float)vidx[(size_t)b * A + a];
      }
      sPD0[tid] = pd0; sPD1[tid] = pd1; sPC[tid] = pcv; sIPF[tid] = ipf;
    }
  }
  __syncthreads();

  // ---- phase B: negative selection ----
  {
    const uint32_t* bc = (const uint32_t*)(ws + W_BCNT) + (size_t)b * NB2;
    uint32_t callv = 0;
    for (int i = tid; i < NB2; i += 256) callv += bc[i];
#pragma unroll
    for (int off = 32; off >= 1; off >>= 1) callv += __shfl_xor(callv, off, 64);
    if (lane == 0) scnt[wid] = callv;
    __syncthreads();
    int call = (int)(scnt[0] + scnt[1] + scnt[2] + scnt[3]);
    int c1 = (int)min(((const uint32_t*)(ws + W_CT1))[b * 16], (uint32_t)CAPN);
    if (c1 <= STG) {
      bitonic_desc((const unsigned long long*)(ws + W_NT1) + (size_t)b * CAPN, c1, stage);
      if (tid < 64) sel[tid] = stage[tid];
      __syncthreads();
    } else {
      select_top64((const unsigned long long*)(ws + W_NT1) + (size_t)b * CAPN, c1,
                   stage, sel, wmax);
    }
    int nn = call < 64 ? call : 64;
    if (nn > c1) nn = c1;   // paranoid clamp; c1>=64 in practice
    if (tid == 0) sNn = nn;
    if (tid < 64) {
      int v = 0;
      if (tid < nn) v = (int)(0xFFFFFFFFu - (uint32_t)sel[tid]);
      sNI[tid] = v;
    }
  }
  __syncthreads();

  // ---- phase C: output assembly ----
  int pn = sPn, nn = sNn;
  if (tid < T) {
    int t = tid;
    bool ispos = t < pn;
    bool isneg = (t >= pn) && (t < pn + nn);
    float tagc = (ispos || isneg) ? 1.0f : 0.0f;
    int tp = t < 63 ? t : 63;
    float d0 = ispos ? sPD0[tp] : 0.0f;
    float d1 = ispos ? sPD1[tp] : 0.0f;
    out[O_DELTAS + ((size_t)b * T + t) * 3 + 0] = d0;
    out[O_DELTAS + ((size_t)b * T + t) * 3 + 1] = d1;
    out[O_DELTAS + ((size_t)b * T + t) * 3 + 2] = tagc;
    out[O_CLS + ((size_t)b * T + t) * 2 + 0] = ispos ? sPC[tp] : 0.0f;
    out[O_CLS + ((size_t)b * T + t) * 2 + 1] = tagc;
    float iv = 0.0f, itag = 0.0f;
    if (ispos) { iv = sIPF[tp]; itag = 1.0f; }
    else if (isneg) {
      int nj = t - pn; nj = nj < 63 ? nj : 63;
      iv = (float)sNI[nj]; itag = -1.0f;
    }
    out[O_IND + ((size_t)b * T + t) * 2 + 0] = iv;
    out[O_IND + ((size_t)b * T + t) * 2 + 1] = itag;
  }
  if (tid >= 128 && tid < 128 + G) {
    int g = tid - 128;
    const float* gp = gt_boxes + ((size_t)b * G + g) * 5;
    float tag = gp[4] > 0.0f ? 1.0f : 0.0f;
    float sd0 = 0.0f, sd1 = 0.0f, si0 = 0.0f, si1 = 0.0f;
    if (tag > 0.0f) {
      unsigned long long lp = ((const unsigned long long*)(ws + W_LEFT))[(size_t)b * G + g];
      unsigned long long rp = ((const unsigned long long*)(ws + W_RIGHT))[(size_t)b * G + g];
      int al = (int)(uint32_t)lp;
      int ar = (int)(0xFFFFFFFFu - (uint32_t)rp);
      float4 la = *(const float4*)(anchors + ((size_t)b * A + al) * 4);
      float4 ra = *(const float4*)(anchors + ((size_t)b * A + ar) * 4);
      sd0 = (gp[1] - (la.w + la.y) * 0.5f) / (la.w - la.y) / 0.1f;
      sd1 = (gp[3] - (ra.w + ra.y) * 0.5f) / (ra.w - ra.y) / 0.1f;
      si0 = (float)vidx[(size_t)b * A + al];
      si1 = (float)vidx[(size_t)b * A + ar];
    }
    out[O_SD + ((size_t)b * G + g) * 3 + 0] = sd0;
    out[O_SD + ((size_t)b * G + g) * 3 + 1] = sd1;
    out[O_SD + ((size_t)b * G + g) * 3 + 2] = tag;
    out[O_SI + ((size_t)b * G + g) * 3 + 0] = si0;
    out[O_SI + ((size_t)b * G + g) * 3 + 1] = si1;
    out[O_SI + ((size_t)b * G + g) * 3 + 2] = tag;
  }
  if (tid == 190) {
    float s = 0.0f;
    for (int g = 0; g < G; ++g)
      s += (gt_boxes[((size_t)b * G + g) * 5 + 4] > 0.0f) ? 1.0f : 0.0f;
    out[O_GTN + b] = s;
  }
  if (tid == 191) out[O_PN + b] = (float)pn;
  if (tid == 192) out[O_NN + b] = (float)nn;
}

extern "C" void kernel_launch(void* const* d_in, const int* in_sizes, int n_in,
                              void* d_out, int out_size, void* d_ws, size_t ws_size,
                              hipStream_t stream) {
  using namespace ct;
  (void)in_sizes; (void)n_in; (void)out_size; (void)ws_size;
  const float* gt_boxes = (const float*)d_in[0];
  const float* gt_cls   = (const float*)d_in[1];
  const float* anchors  = (const float*)d_in[2];
  const int*   vidx     = (const int*)d_in[3];
  float* out = (float*)d_out;
  char* ws = (char*)d_ws;

  k01_init<<<dim3(B), dim3(256), 0, stream>>>(gt_boxes, ws);
  k1b_gtmax<<<dim3(NB2, B), dim3(256), 0, stream>>>(anchors, gt_boxes, ws);
  k2_posneg<<<dim3(NB2, B), dim3(256), 0, stream>>>(anchors, gt_boxes, ws);
  k345_out<<<dim3(B), dim3(256), 0, stream>>>(anchors, gt_boxes, gt_cls, vidx, ws, out);
}